// Round 10
// baseline (1123.758 us; speedup 1.0000x reference)
//
#include <hip/hip_runtime.h>
#include <stdint.h>

typedef float f32x4 __attribute__((ext_vector_type(4)));
typedef short s16x8 __attribute__((ext_vector_type(8)));
typedef unsigned long long u64;

__device__ __forceinline__ unsigned short f2bf(float f) {
  union { float f; unsigned u; } v; v.f = f;
  unsigned u = v.u;
  return (unsigned short)((u + 0x7FFFu + ((u >> 16) & 1u)) >> 16);
}
__device__ __forceinline__ float bf2f(unsigned short b) {
  union { unsigned u; float f; } v; v.u = ((unsigned)b) << 16; return v.f;
}

// ---------------- conv4: 3x3, 512->512, 64x64, SAME, K-split x4 --------------
#define CONV_ICC 8
__global__ __launch_bounds__(256, 2) void k_conv4(const float* __restrict__ fm,
                                                  const float* __restrict__ w,
                                                  float* __restrict__ ypart) {
  __shared__ float Xs[2][CONV_ICC * 342];     // [buf][ic][18 rows][pitch 19]
  __shared__ float Ws[2][CONV_ICC * 9 * 64];  // [buf][ic][k][oc]
  int bid = blockIdx.x;
  int s = bid & 3, ocg = (bid >> 2) & 7, sp = bid >> 5;   // sp 0..15
  int h0 = (sp >> 2) * 16, w0 = (sp & 3) * 16;
  int oc0 = ocg * 64;
  int t = threadIdx.x;
  int g = t >> 5, p = t & 31;
  int row = p >> 1, colb = (p & 1) * 8;

  int xic[11], xoff[11], xlds[11]; bool xval[11], xact[11];
  #pragma unroll
  for (int i = 0; i < 11; i++) {
    int idx = t + i * 256;
    xact[i] = (idx < CONV_ICC * 324);
    if (xact[i]) {
      int ic = idx / 324, rem = idx - ic * 324;
      int r = rem / 18, cc = rem - r * 18;
      int gy = h0 + r - 1, gx = w0 + cc - 1;
      xval[i] = ((unsigned)gy < 64u) && ((unsigned)gx < 64u);
      xic[i] = ic;
      xoff[i] = xval[i] ? (gy * 64 + gx) : 0;
      xlds[i] = ic * 342 + r * 19 + cc;
    } else { xval[i] = false; xic[i] = 0; xoff[i] = 0; xlds[i] = 0; }
  }
  u64 wbase[18];
  #pragma unroll
  for (int i = 0; i < 18; i++) {
    int idx = t + i * 256;
    int oc = idx & 63, rest = idx >> 6;
    int ic = rest / 9, kk = rest - ic * 9;
    wbase[i] = (u64)(oc0 + oc) * 4608 + ic * 9 + kk;
  }

  float acc[8][8] = {};
  int cbase = s * 128;
  float XR[11], WR[18];

  {
    int c0 = cbase;
    #pragma unroll
    for (int i = 0; i < 11; i++)
      XR[i] = xval[i] ? fm[(u64)(c0 + xic[i]) * 4096 + xoff[i]] : 0.f;
    #pragma unroll
    for (int i = 0; i < 18; i++)
      WR[i] = w[wbase[i] + (u64)c0 * 9];
    #pragma unroll
    for (int i = 0; i < 11; i++) if (xact[i]) Xs[0][xlds[i]] = XR[i];
    #pragma unroll
    for (int i = 0; i < 18; i++) Ws[0][t + i * 256] = WR[i];
  }
  __syncthreads();

  int cur = 0;
  for (int chunk = 0; chunk < 16; chunk++) {
    bool pf = (chunk < 15);
    if (pf) {
      int cn = cbase + (chunk + 1) * CONV_ICC;
      #pragma unroll
      for (int i = 0; i < 11; i++)
        XR[i] = xval[i] ? fm[(u64)(cn + xic[i]) * 4096 + xoff[i]] : 0.f;
      #pragma unroll
      for (int i = 0; i < 18; i++)
        WR[i] = w[wbase[i] + (u64)cn * 9];
    }
    const float* XsC = Xs[cur];
    const float* WsC = Ws[cur];
    for (int ic = 0; ic < CONV_ICC; ic++) {
      const float* xb = &XsC[ic * 342 + colb];
      float xr[3][10];
      #pragma unroll
      for (int r = 0; r < 3; r++)
        #pragma unroll
        for (int j = 0; j < 10; j++)
          xr[r][j] = xb[(row + r) * 19 + j];
      #pragma unroll
      for (int kh = 0; kh < 3; kh++) {
        #pragma unroll
        for (int kw = 0; kw < 3; kw++) {
          const float* wp = &WsC[(ic * 9 + kh * 3 + kw) * 64 + g * 8];
          f32x4 wa = *(const f32x4*)wp;
          f32x4 wb = *(const f32x4*)(wp + 4);
          float wv[8] = {wa.x, wa.y, wa.z, wa.w, wb.x, wb.y, wb.z, wb.w};
          #pragma unroll
          for (int o = 0; o < 8; o++) {
            #pragma unroll
            for (int j = 0; j < 8; j++) {
              acc[o][j] += wv[o] * xr[kh][kw + j];
            }
          }
        }
      }
    }
    if (pf) {
      #pragma unroll
      for (int i = 0; i < 11; i++) if (xact[i]) Xs[cur ^ 1][xlds[i]] = XR[i];
      #pragma unroll
      for (int i = 0; i < 18; i++) Ws[cur ^ 1][t + i * 256] = WR[i];
    }
    __syncthreads();
    cur ^= 1;
  }

  float* yp = ypart + (u64)s * 2097152;
  #pragma unroll
  for (int j = 0; j < 8; j++) {
    int pxg = (h0 + row) * 64 + (w0 + colb + j);
    f32x4 v0, v1;
    v0.x = acc[0][j]; v0.y = acc[1][j]; v0.z = acc[2][j]; v0.w = acc[3][j];
    v1.x = acc[4][j]; v1.y = acc[5][j]; v1.z = acc[6][j]; v1.w = acc[7][j];
    f32x4* dst = (f32x4*)&yp[(u64)pxg * 512 + oc0 + g * 8];
    dst[0] = v0; dst[1] = v1;
  }
}

// --------------- 1x1 convs: sum partials + bias + relu, then dots ------------
__global__ __launch_bounds__(256) void k_rpn1x1(const float* __restrict__ ypart,
                                                const float* __restrict__ conv_b,
                                                const float* __restrict__ cw, const float* __restrict__ cb,
                                                const float* __restrict__ bw, const float* __restrict__ bb,
                                                float* __restrict__ out_s, float* __restrict__ out_d) {
  __shared__ float Ys[16 * 516];
  int px0 = blockIdx.x * 16;
  int t = threadIdx.x;
  for (int c = t; c < 16 * 128; c += 256) {
    int p = c >> 7, seg = c & 127;
    u64 off = (u64)(px0 + p) * 512 + seg * 4;
    f32x4 v0 = *(const f32x4*)&ypart[off];
    f32x4 v1 = *(const f32x4*)&ypart[2097152 + off];
    f32x4 v2 = *(const f32x4*)&ypart[2 * 2097152 + off];
    f32x4 v3 = *(const f32x4*)&ypart[3 * (u64)2097152 + off];
    f32x4 b = *(const f32x4*)&conv_b[seg * 4];
    f32x4 r;
    r.x = fmaxf(v0.x + v1.x + v2.x + v3.x + b.x, 0.f);
    r.y = fmaxf(v0.y + v1.y + v2.y + v3.y + b.y, 0.f);
    r.z = fmaxf(v0.z + v1.z + v2.z + v3.z + b.z, 0.f);
    r.w = fmaxf(v0.w + v1.w + v2.w + v3.w + b.w, 0.f);
    *(f32x4*)&Ys[p * 516 + seg * 4] = r;
  }
  __syncthreads();
  int px = t & 15, og = t >> 4;
  const float* yr = &Ys[px * 516];
  for (int n = og; n < 45; n += 16) {
    const float* wr = (n < 9) ? &cw[n * 512] : &bw[(n - 9) * 512];
    float acc = 0.f;
    for (int k = 0; k < 512; k += 4) {
      f32x4 wv = *(const f32x4*)&wr[k];
      acc += wv.x * yr[k] + wv.y * yr[k + 1] + wv.z * yr[k + 2] + wv.w * yr[k + 3];
    }
    int gpx = px0 + px;
    if (n < 9) {
      float s = acc + cb[n];
      out_s[gpx * 9 + n] = 1.f / (1.f + expf(-s));
    } else {
      out_d[gpx * 36 + (n - 9)] = acc + bb[n - 9];
    }
  }
}

// --------------- box decode + sort keys --------------------------------------
__global__ void k_decode(const float* __restrict__ sc, const float* __restrict__ dl,
                         const float* __restrict__ amap,
                         float* __restrict__ boxes, u64* __restrict__ keys) {
  int i = blockIdx.x * 256 + threadIdx.x;
  if (i >= 65536) return;
  if (i < 36864) {
    int px = i / 9, a = i - px * 9;
    const float* A = &amap[i * 4];
    const float* D = &dl[px * 36 + a * 4];
    float cy = A[0] + D[0] * A[2];
    float cx = A[1] + D[1] * A[3];
    float hh = A[2] * expf(D[2]);
    float ww = A[3] * expf(D[3]);
    float y1 = fminf(fmaxf(cy - 0.5f * hh, 0.f), 1023.f);
    float x1 = fminf(fmaxf(cx - 0.5f * ww, 0.f), 1023.f);
    float y2 = fminf(fmaxf(cy + 0.5f * hh, 0.f), 1023.f);
    float x2 = fminf(fmaxf(cx + 0.5f * ww, 0.f), 1023.f);
    f32x4 v; v.x = y1; v.y = x1; v.z = y2; v.w = x2;
    *(f32x4*)&boxes[i * 4] = v;
    unsigned bits = __float_as_uint(sc[i]);
    u64 key = ((u64)bits << 16) | (u64)(0xFFFFu - (unsigned)i);
    keys[i] = ~key;  // ascending sort of ~key == descending by (score, -idx)
  } else {
    keys[i] = ~0ull;
  }
}

// --------------- bitonic sort of 65536 u64 keys (ascending) ------------------
__global__ __launch_bounds__(1024) void k_sort_local(u64* __restrict__ keys) {
  __shared__ u64 S[8192];
  int base = blockIdx.x * 8192;
  for (int i = threadIdx.x; i < 8192; i += 1024) S[i] = keys[base + i];
  __syncthreads();
  for (int k = 2; k <= 8192; k <<= 1) {
    for (int j = k >> 1; j > 0; j >>= 1) {
      for (int p = threadIdx.x; p < 4096; p += 1024) {
        int i = ((p & ~(j - 1)) << 1) | (p & (j - 1));
        int ix = i | j;
        bool up = (((base + i) & k) == 0);
        u64 a = S[i], c = S[ix];
        if ((a > c) == up) { S[i] = c; S[ix] = a; }
      }
      __syncthreads();
    }
  }
  for (int i = threadIdx.x; i < 8192; i += 1024) keys[base + i] = S[i];
}

__global__ void k_sort_global(u64* __restrict__ keys, int k, int j) {
  int p = blockIdx.x * 256 + threadIdx.x;
  int i = ((p & ~(j - 1)) << 1) | (p & (j - 1));
  int ix = i | j;
  bool up = ((i & k) == 0);
  u64 a = keys[i], c = keys[ix];
  if ((a > c) == up) { keys[i] = c; keys[ix] = a; }
}

__global__ __launch_bounds__(1024) void k_sort_merge(u64* __restrict__ keys, int k) {
  __shared__ u64 S[8192];
  int base = blockIdx.x * 8192;
  for (int i = threadIdx.x; i < 8192; i += 1024) S[i] = keys[base + i];
  __syncthreads();
  for (int j = 4096; j > 0; j >>= 1) {
    for (int p = threadIdx.x; p < 4096; p += 1024) {
      int i = ((p & ~(j - 1)) << 1) | (p & (j - 1));
      int ix = i | j;
      bool up = (((base + i) & k) == 0);
      u64 a = S[i], c = S[ix];
      if ((a > c) == up) { S[i] = c; S[ix] = a; }
    }
    __syncthreads();
  }
  for (int i = threadIdx.x; i < 8192; i += 1024) keys[base + i] = S[i];
}

__global__ void k_gather_sorted(const u64* __restrict__ keys, const float* __restrict__ boxes,
                                float* __restrict__ bx) {
  int p = blockIdx.x * 256 + threadIdx.x;
  if (p >= 6000) return;
  u64 key = ~keys[p];
  int idx = 0xFFFF - (int)(key & 0xFFFFull);
  *(f32x4*)&bx[p * 4] = *(const f32x4*)&boxes[idx * 4];
}

// --------------- NMS: suppression bitmask + sequential scan ------------------
__global__ __launch_bounds__(128) void k_nms_mask(const float* __restrict__ bx, u64* __restrict__ mask) {
  int i = blockIdx.x;
  int w = threadIdx.x;
  if (w >= 94) return;
  f32x4 bi = *(const f32x4*)&bx[i * 4];
  float ai = (bi.z - bi.x) * (bi.w - bi.y);
  u64 m = 0;
  int j0 = w * 64;
  for (int b = 0; b < 64; b++) {
    int j = j0 + b;
    if (j >= 6000) break;
    if (j <= i) continue;
    f32x4 bj = *(const f32x4*)&bx[j * 4];
    float yy1 = fmaxf(bi.x, bj.x), xx1 = fmaxf(bi.y, bj.y);
    float yy2 = fminf(bi.z, bj.z), xx2 = fminf(bi.w, bj.w);
    float inter = fmaxf(yy2 - yy1, 0.f) * fmaxf(xx2 - xx1, 0.f);
    float aj = (bj.z - bj.x) * (bj.w - bj.y);
    float iou = inter / (ai + aj - inter + 1e-8f);
    if (iou > 0.7f) m |= (1ull << b);
  }
  mask[i * 94 + w] = m;
}

// Sequential greedy scan with EARLY EXIT (see R1 notes).
__global__ __launch_bounds__(64) void k_nms_scan(const u64* __restrict__ mask, int* __restrict__ sel) {
  int lane = threadIdx.x;
  u64 rem0 = 0, rem1 = 0;
  int nkeep = 0;
  u64 cur0[16], cur1[16], nxt0[16], nxt1[16];
  bool l30 = (lane < 30);
  #pragma unroll
  for (int r = 0; r < 16; r++) {
    cur0[r] = mask[r * 94 + lane];
    cur1[r] = l30 ? mask[r * 94 + 64 + lane] : 0ull;
  }
  for (int c0 = 0; c0 < 6000; c0 += 16) {
    int n0 = c0 + 16;
    if (n0 < 6000) {
      #pragma unroll
      for (int r = 0; r < 16; r++) {
        nxt0[r] = mask[(n0 + r) * 94 + lane];
        nxt1[r] = l30 ? mask[(n0 + r) * 94 + 64 + lane] : 0ull;
      }
    }
    #pragma unroll
    for (int r = 0; r < 16; r++) {
      int i = c0 + r;
      int wi = i >> 6, bi = i & 63;
      u64 wv = (wi < 64) ? __shfl(rem0, wi, 64) : __shfl(rem1, wi - 64, 64);
      if (!((wv >> bi) & 1ull)) {
        if (lane == 0 && nkeep < 300) sel[nkeep] = i;
        nkeep++;
        rem0 |= cur0[r]; rem1 |= cur1[r];
      }
    }
    if (nkeep >= 300) return;
    #pragma unroll
    for (int r = 0; r < 16; r++) { cur0[r] = nxt0[r]; cur1[r] = nxt1[r]; }
  }
  __shared__ u64 remS[94];
  remS[lane] = rem0;
  if (l30) remS[64 + lane] = rem1;
  __syncthreads();
  if (lane == 0) {
    int k = nkeep;
    for (int i = 0; i < 6000 && k < 300; i++) {
      if ((remS[i >> 6] >> (i & 63)) & 1ull) sel[k++] = i;
    }
  }
}

__global__ void k_gather_prop(const int* __restrict__ sel, const float* __restrict__ bx,
                              float* __restrict__ out_p, float* __restrict__ rois) {
  int r = blockIdx.x * 64 + threadIdx.x;
  if (r >= 300) return;
  int p = sel[r];
  float y1 = bx[p * 4 + 0], x1 = bx[p * 4 + 1], y2 = bx[p * 4 + 2], x2 = bx[p * 4 + 3];
  out_p[r * 4 + 0] = y1; out_p[r * 4 + 1] = x1; out_p[r * 4 + 2] = y2; out_p[r * 4 + 3] = x2;
  rois[r * 4 + 0] = x1; rois[r * 4 + 1] = y1; rois[r * 4 + 2] = x2; rois[r * 4 + 3] = y2;
}

// --------------- ROI max-pool 7x7 (exact ref semantics), out bf16 ------------
__global__ __launch_bounds__(256) void k_roipool(const float* __restrict__ fm,
                                                 const float* __restrict__ rois,
                                                 unsigned short* __restrict__ pooled) {
  int roi = blockIdx.x / 98;
  int seg = blockIdx.x - roi * 98;
  __shared__ int hs[7], he[7], wls[7], wle[7];
  if (threadIdx.x < 28) {
    int kind = threadIdx.x / 7, p = threadIdx.x - kind * 7;
    float x1 = rintf(rois[roi * 4 + 0] * 0.0625f);
    float y1 = rintf(rois[roi * 4 + 1] * 0.0625f);
    float x2 = rintf(rois[roi * 4 + 2] * 0.0625f);
    float y2 = rintf(rois[roi * 4 + 3] * 0.0625f);
    float rw = fmaxf(x2 - x1 + 1.f, 1.f), rh = fmaxf(y2 - y1 + 1.f, 1.f);
    float bh = rh / 7.f, bw = rw / 7.f;
    float fp = (float)p;
    if (kind == 0) hs[p]  = (int)fminf(fmaxf(floorf(fp * bh) + y1, 0.f), 64.f);
    if (kind == 1) he[p]  = (int)fminf(fmaxf(ceilf((fp + 1.f) * bh) + y1, 0.f), 64.f);
    if (kind == 2) wls[p] = (int)fminf(fmaxf(floorf(fp * bw) + x1, 0.f), 64.f);
    if (kind == 3) wle[p] = (int)fminf(fmaxf(ceilf((fp + 1.f) * bw) + x1, 0.f), 64.f);
  }
  __syncthreads();
  int o = seg * 256 + threadIdx.x;  // < 25088
  int c = o / 49; int cell = o - c * 49;
  int ph = cell / 7, pw = cell - ph * 7;
  int y0 = hs[ph], y1e = he[ph], x0 = wls[pw], x1e = wle[pw];
  bool any = (y1e > y0) && (x1e > x0);
  float m = -1e30f;
  const float* base = &fm[c * 4096];
  for (int yy = y0; yy < y1e; yy++)
    for (int xx = x0; xx < x1e; xx++)
      m = fmaxf(m, base[yy * 64 + xx]);
  pooled[(u64)roi * 25088 + o] = f2bf(any ? m : 0.f);
}

// --------------- bf16 cast prepass (contiguous stream) -----------------------
// Same f2bf rounding as the in-kernel convert -> bit-identical gemm output.
// Output (<=206MB) is Infinity-Cache-resident for the following gemm.
__global__ __launch_bounds__(256) void k_bf16_cast(const float* __restrict__ in,
                                                   unsigned short* __restrict__ out, int n) {
  int stride = gridDim.x * 256 * 8;
  for (int i = (blockIdx.x * 256 + threadIdx.x) * 8; i < n; i += stride) {
    f32x4 a = *(const f32x4*)&in[i];
    f32x4 b = *(const f32x4*)&in[i + 4];
    s16x8 pk;
    pk[0] = (short)f2bf(a.x); pk[1] = (short)f2bf(a.y); pk[2] = (short)f2bf(a.z); pk[3] = (short)f2bf(a.w);
    pk[4] = (short)f2bf(b.x); pk[5] = (short)f2bf(b.y); pk[6] = (short)f2bf(b.z); pk[7] = (short)f2bf(b.w);
    *(s16x8*)&out[i] = pk;
  }
}

// --------------- big GEMM v4b: bf16-B (L3-resident), depth-2 pipeline --------
// C[320][N] += A_bf16[320][K] * Bbf_bf16[N][K]^T. Grid (N/128, S), 512 thr.
#define GEMM_ITERB(IT, BSLOT)                                                       \
  {                                                                                 \
    bool pf = ((IT) + 1 < n_it);                                                    \
    if (pf) {                                                                       \
      int kn = kbeg + ((IT) + 1) * 64;                                              \
      _Pragma("unroll")                                                             \
      for (int i = 0; i < 5; i++)                                                   \
        Araw[i] = *(const uint4*)&A[(u64)am[i] * K + kn + aks[i] * 8];              \
    }                                                                               \
    const unsigned short* ab = (const unsigned short*)Ab[cur];                      \
    const unsigned short* bb = (const unsigned short*)Bb[cur];                      \
    _Pragma("unroll")                                                               \
    for (int ksub = 0; ksub < 2; ksub++) {                                          \
      int ks = ksub * 4 + lk;                                                       \
      s16x8 bf0 = *(const s16x8*)&bb[(u64)(ks * 128 + ng * 32 + lr) * 8];           \
      s16x8 bf1 = *(const s16x8*)&bb[(u64)(ks * 128 + ng * 32 + 16 + lr) * 8];      \
      _Pragma("unroll")                                                             \
      for (int mt = 0; mt < 10; mt++) {                                             \
        s16x8 af = *(const s16x8*)&ab[(u64)(ks * 320 + m0 + mt * 16 + lr) * 8];     \
        acc[mt][0] = __builtin_amdgcn_mfma_f32_16x16x32_bf16(af, bf0, acc[mt][0], 0, 0, 0); \
        acc[mt][1] = __builtin_amdgcn_mfma_f32_16x16x32_bf16(af, bf1, acc[mt][1], 0, 0, 0); \
      }                                                                             \
    }                                                                               \
    if (pf) {                                                                       \
      _Pragma("unroll")                                                             \
      for (int i = 0; i < 5; i++) Ab[cur ^ 1][t + i * 512] = Araw[i];               \
      Bb[cur ^ 1][(bpart * 2 + 0) * 128 + brow] = BSLOT[0];                         \
      Bb[cur ^ 1][(bpart * 2 + 1) * 128 + brow] = BSLOT[1];                         \
      if ((IT) + 3 < n_it) {                                                        \
        int k3 = kbeg + ((IT) + 3) * 64;                                            \
        BSLOT[0] = *(const uint4*)&gB[k3];                                          \
        BSLOT[1] = *(const uint4*)&gB[k3 + 8];                                      \
      }                                                                             \
    }                                                                               \
    __syncthreads();                                                                \
    cur ^= 1;                                                                       \
  }

__global__ __launch_bounds__(512, 1) void k_gemm4b(const unsigned short* __restrict__ A,
                                                   const unsigned short* __restrict__ Bbf,
                                                   float* __restrict__ Cpre,
                                                   int K, int Kslice, int N) {
  __shared__ uint4 Ab[2][2560];   // [buf][kseg*320 + m]
  __shared__ uint4 Bb[2][1024];   // [buf][kseg*128 + row]
  int n0 = blockIdx.x * 128;
  int s = blockIdx.y;
  int t = threadIdx.x;
  int wave = t >> 6, lane = t & 63;
  int mg = wave & 1, ng = wave >> 1;
  int m0 = mg * 160;
  int lr = lane & 15, lk = lane >> 4;

  int am[5], aks[5];
  #pragma unroll
  for (int i = 0; i < 5; i++) { int idx = t + i * 512; am[i] = idx % 320; aks[i] = idx / 320; }
  int brow = t >> 2, bpart = t & 3;
  const unsigned short* gB = &Bbf[(u64)(n0 + brow) * K + bpart * 16];

  f32x4 acc[10][2];
  #pragma unroll
  for (int mt = 0; mt < 10; mt++)
    for (int nt = 0; nt < 2; nt++) { acc[mt][nt].x = 0; acc[mt][nt].y = 0; acc[mt][nt].z = 0; acc[mt][nt].w = 0; }

  int kbeg = s * Kslice;
  int n_it = Kslice >> 6;
  uint4 Araw[5];
  uint4 B0[2], B1[2];   // B(k) lives in slot k&1

  #pragma unroll
  for (int i = 0; i < 5; i++)
    Araw[i] = *(const uint4*)&A[(u64)am[i] * K + kbeg + aks[i] * 8];
  B0[0] = *(const uint4*)&gB[kbeg];
  B0[1] = *(const uint4*)&gB[kbeg + 8];
  #pragma unroll
  for (int i = 0; i < 5; i++) Ab[0][t + i * 512] = Araw[i];
  Bb[0][(bpart * 2 + 0) * 128 + brow] = B0[0];
  Bb[0][(bpart * 2 + 1) * 128 + brow] = B0[1];
  if (1 < n_it) {
    B1[0] = *(const uint4*)&gB[kbeg + 64];
    B1[1] = *(const uint4*)&gB[kbeg + 64 + 8];
  }
  if (2 < n_it) {
    B0[0] = *(const uint4*)&gB[kbeg + 128];
    B0[1] = *(const uint4*)&gB[kbeg + 128 + 8];
  }
  __syncthreads();

  int cur = 0;
  for (int itp = 0; itp < n_it; itp += 2) {
    GEMM_ITERB(itp, B1);
    if (itp + 1 < n_it) GEMM_ITERB(itp + 1, B0);
  }

  #pragma unroll
  for (int mt = 0; mt < 10; mt++)
    for (int nt = 0; nt < 2; nt++)
      for (int r = 0; r < 4; r++) {
        int m = m0 + mt * 16 + lk * 4 + r;
        int n = n0 + ng * 32 + nt * 16 + lr;
        atomicAdd(&Cpre[(u64)m * N + n], acc[mt][nt][r]);
      }
}

// --------------- fallback GEMM (f32 B, converts in-kernel) -------------------
#define GEMM_ITERF(IT, BSLOT)                                                       \
  {                                                                                 \
    bool pf = ((IT) + 1 < n_it);                                                    \
    if (pf) {                                                                       \
      int kn = kbeg + ((IT) + 1) * 64;                                              \
      _Pragma("unroll")                                                             \
      for (int i = 0; i < 5; i++)                                                   \
        Araw[i] = *(const uint4*)&A[(u64)am[i] * K + kn + aks[i] * 8];              \
    }                                                                               \
    const unsigned short* ab = (const unsigned short*)Ab[cur];                      \
    const unsigned short* bb = (const unsigned short*)Bb[cur];                      \
    _Pragma("unroll")                                                               \
    for (int ksub = 0; ksub < 2; ksub++) {                                          \
      int ks = ksub * 4 + lk;                                                       \
      s16x8 bf0 = *(const s16x8*)&bb[(u64)(ks * 128 + ng * 32 + lr) * 8];           \
      s16x8 bf1 = *(const s16x8*)&bb[(u64)(ks * 128 + ng * 32 + 16 + lr) * 8];      \
      _Pragma("unroll")                                                             \
      for (int mt = 0; mt < 10; mt++) {                                             \
        s16x8 af = *(const s16x8*)&ab[(u64)(ks * 320 + m0 + mt * 16 + lr) * 8];     \
        acc[mt][0] = __builtin_amdgcn_mfma_f32_16x16x32_bf16(af, bf0, acc[mt][0], 0, 0, 0); \
        acc[mt][1] = __builtin_amdgcn_mfma_f32_16x16x32_bf16(af, bf1, acc[mt][1], 0, 0, 0); \
      }                                                                             \
    }                                                                               \
    if (pf) {                                                                       \
      _Pragma("unroll")                                                             \
      for (int i = 0; i < 5; i++) Ab[cur ^ 1][t + i * 512] = Araw[i];               \
      float fv[16] = {BSLOT[0].x, BSLOT[0].y, BSLOT[0].z, BSLOT[0].w,               \
                      BSLOT[1].x, BSLOT[1].y, BSLOT[1].z, BSLOT[1].w,               \
                      BSLOT[2].x, BSLOT[2].y, BSLOT[2].z, BSLOT[2].w,               \
                      BSLOT[3].x, BSLOT[3].y, BSLOT[3].z, BSLOT[3].w};              \
      _Pragma("unroll")                                                             \
      for (int h = 0; h < 2; h++) {                                                 \
        s16x8 pk;                                                                   \
        _Pragma("unroll")                                                           \
        for (int j = 0; j < 8; j++) pk[j] = (short)f2bf(fv[h * 8 + j]);             \
        *(s16x8*)&Bb[cur ^ 1][(bpart * 2 + h) * 128 + brow] = pk;                   \
      }                                                                             \
      if ((IT) + 3 < n_it) {                                                        \
        int k3 = kbeg + ((IT) + 3) * 64;                                            \
        _Pragma("unroll")                                                           \
        for (int q = 0; q < 4; q++) BSLOT[q] = *(const f32x4*)&gB[k3 + q * 4];      \
      }                                                                             \
    }                                                                               \
    __syncthreads();                                                                \
    cur ^= 1;                                                                       \
  }

__global__ __launch_bounds__(512, 1) void k_gemm4f(const unsigned short* __restrict__ A,
                                                   const float* __restrict__ B,
                                                   float* __restrict__ Cpre,
                                                   int K, int Kslice, int N) {
  __shared__ uint4 Ab[2][2560];
  __shared__ uint4 Bb[2][1024];
  int n0 = blockIdx.x * 128;
  int s = blockIdx.y;
  int t = threadIdx.x;
  int wave = t >> 6, lane = t & 63;
  int mg = wave & 1, ng = wave >> 1;
  int m0 = mg * 160;
  int lr = lane & 15, lk = lane >> 4;

  int am[5], aks[5];
  #pragma unroll
  for (int i = 0; i < 5; i++) { int idx = t + i * 512; am[i] = idx % 320; aks[i] = idx / 320; }
  int brow = t >> 2, bpart = t & 3;
  const float* gB = &B[(u64)(n0 + brow) * K + bpart * 16];

  f32x4 acc[10][2];
  #pragma unroll
  for (int mt = 0; mt < 10; mt++)
    for (int nt = 0; nt < 2; nt++) { acc[mt][nt].x = 0; acc[mt][nt].y = 0; acc[mt][nt].z = 0; acc[mt][nt].w = 0; }

  int kbeg = s * Kslice;
  int n_it = Kslice >> 6;
  uint4 Araw[5];
  f32x4 Braw0[4], Braw1[4];

  #pragma unroll
  for (int i = 0; i < 5; i++)
    Araw[i] = *(const uint4*)&A[(u64)am[i] * K + kbeg + aks[i] * 8];
  #pragma unroll
  for (int q = 0; q < 4; q++)
    Braw0[q] = *(const f32x4*)&gB[kbeg + q * 4];
  #pragma unroll
  for (int i = 0; i < 5; i++) Ab[0][t + i * 512] = Araw[i];
  {
    float fv[16] = {Braw0[0].x, Braw0[0].y, Braw0[0].z, Braw0[0].w,
                    Braw0[1].x, Braw0[1].y, Braw0[1].z, Braw0[1].w,
                    Braw0[2].x, Braw0[2].y, Braw0[2].z, Braw0[2].w,
                    Braw0[3].x, Braw0[3].y, Braw0[3].z, Braw0[3].w};
    #pragma unroll
    for (int h = 0; h < 2; h++) {
      s16x8 pk;
      #pragma unroll
      for (int j = 0; j < 8; j++) pk[j] = (short)f2bf(fv[h * 8 + j]);
      *(s16x8*)&Bb[0][(bpart * 2 + h) * 128 + brow] = pk;
    }
  }
  if (1 < n_it) {
    #pragma unroll
    for (int q = 0; q < 4; q++) Braw1[q] = *(const f32x4*)&gB[kbeg + 64 + q * 4];
  }
  if (2 < n_it) {
    #pragma unroll
    for (int q = 0; q < 4; q++) Braw0[q] = *(const f32x4*)&gB[kbeg + 128 + q * 4];
  }
  __syncthreads();

  int cur = 0;
  for (int itp = 0; itp < n_it; itp += 2) {
    GEMM_ITERF(itp, Braw1);
    if (itp + 1 < n_it) GEMM_ITERF(itp + 1, Braw0);
  }

  #pragma unroll
  for (int mt = 0; mt < 10; mt++)
    for (int nt = 0; nt < 2; nt++)
      for (int r = 0; r < 4; r++) {
        int m = m0 + mt * 16 + lk * 4 + r;
        int n = n0 + ng * 32 + nt * 16 + lr;
        atomicAdd(&Cpre[(u64)m * N + n], acc[mt][nt][r]);
      }
}

__global__ void k_bias_relu_bf(const float* __restrict__ pre, const float* __restrict__ bias,
                               unsigned short* __restrict__ outb) {
  int i = blockIdx.x * 256 + threadIdx.x;  // 320*4096 total
  float v = pre[i] + bias[i & 4095];
  outb[i] = f2bf(fmaxf(v, 0.f));
}

// --------------- heads: cls softmax + reg ------------------------------------
__global__ __launch_bounds__(128) void k_head(const unsigned short* __restrict__ h2,
                                              const float* __restrict__ cw, const float* __restrict__ cb,
                                              const float* __restrict__ rw, const float* __restrict__ rb,
                                              float* __restrict__ out_cls, float* __restrict__ out_reg) {
  __shared__ float Hs[4096];
  __shared__ float logits[101];
  __shared__ float es[21];
  int r = blockIdx.x, t = threadIdx.x;
  for (int c = t; c < 512; c += 128) {
    uint4 raw = *(const uint4*)&h2[(u64)r * 4096 + c * 8];
    unsigned short* sp = (unsigned short*)&raw;
    #pragma unroll
    for (int q = 0; q < 8; q++) Hs[c * 8 + q] = bf2f(sp[q]);
  }
  __syncthreads();
  for (int n = t; n < 101; n += 128) {
    const float* wrow = (n < 21) ? &cw[n * 4096] : &rw[(n - 21) * 4096];
    float acc = 0.f;
    for (int k = 0; k < 4096; k += 4) {
      f32x4 wv = *(const f32x4*)&wrow[k];
      acc += wv.x * Hs[k] + wv.y * Hs[k + 1] + wv.z * Hs[k + 2] + wv.w * Hs[k + 3];
    }
    acc += (n < 21) ? cb[n] : rb[n - 21];
    logits[n] = acc;
  }
  __syncthreads();
  if (t < 21) {
    float mx = logits[0];
    for (int q = 1; q < 21; q++) mx = fmaxf(mx, logits[q]);
    es[t] = expf(logits[t] - mx);
  }
  __syncthreads();
  if (t < 21) {
    float sum = 0.f;
    for (int q = 0; q < 21; q++) sum += es[q];
    out_cls[r * 21 + t] = es[t] / sum;
  }
  if (t >= 21 && t < 101) out_reg[r * 80 + (t - 21)] = logits[t];
}

// ------------------------------- launcher ------------------------------------
extern "C" void kernel_launch(void* const* d_in, const int* in_sizes, int n_in,
                              void* d_out, int out_size, void* d_ws, size_t ws_size,
                              hipStream_t stream) {
  (void)in_sizes; (void)n_in; (void)out_size;
  const float* fm     = (const float*)d_in[0];
  const float* amap   = (const float*)d_in[1];
  const float* conv_w = (const float*)d_in[3];
  const float* conv_b = (const float*)d_in[4];
  const float* cls_w  = (const float*)d_in[5];
  const float* cls_b  = (const float*)d_in[6];
  const float* box_w  = (const float*)d_in[7];
  const float* box_b  = (const float*)d_in[8];
  const float* fc1_w  = (const float*)d_in[9];
  const float* fc1_b  = (const float*)d_in[10];
  const float* fc2_w  = (const float*)d_in[11];
  const float* fc2_b  = (const float*)d_in[12];
  const float* cw     = (const float*)d_in[13];
  const float* cbias  = (const float*)d_in[14];
  const float* rw     = (const float*)d_in[15];
  const float* rbias  = (const float*)d_in[16];

  float* out_s = (float*)d_out;           // 36864
  float* out_d = out_s + 36864;           // 147456
  float* out_p = out_d + 147456;          // 1200
  float* out_c = out_p + 1200;            // 6300
  float* out_r = out_c + 6300;            // 24000

  char* ws = (char*)d_ws;
  // Overlay: ypart [0, 33,554,432) lives only conv4 -> rpn1x1.
  float* ypart = (float*)(ws + 0);                          // 4 x 8,388,608
  u64*   mask  = (u64*)  (ws + 0);                          // 4,512,000 (post-rpn1x1)
  unsigned short* pooled = (unsigned short*)(ws + 4718592); // 16,056,320 -> ends 20,774,912
  float* boxes = (float*)(ws + 20971520);                   // 589,824 -> 21,561,344
  u64*   keys  = (u64*)  (ws + 21561344);                   // 524,288 -> 22,085,632
  float* bx    = (float*)(ws + 22085632);                   // 96,000 -> 22,181,632
  int*   sel   = (int*)  (ws + 22181632);                   // 1,280
  float* rois  = (float*)(ws + 22182912);                   // 4,800
  float* h1pre = (float*)(ws + 22282240);                   // 5,242,880 -> 27,525,120
  unsigned short* h1bf = (unsigned short*)(ws + 27525120);  // 2,621,440 -> 30,146,560
  float* h2pre = h1pre;                                     // alias (re-zeroed mid-stream)
  unsigned short* h2bf = (unsigned short*)(ws + 30146560);  // 2,621,440 -> 32,768,000
  // bf16 weight images (past all overlays):
  unsigned short* fc1bf = (unsigned short*)(ws + 33554432); // 205,520,896 -> 239,075,328
  unsigned short* fc2bf = (unsigned short*)(ws + 239075328);// 33,554,432 -> 272,629,760
  bool fast = (ws_size >= (size_t)272629760ull);

  k_conv4<<<512, 256, 0, stream>>>(fm, conv_w, ypart);
  k_rpn1x1<<<256, 256, 0, stream>>>(ypart, conv_b, cls_w, cls_b, box_w, box_b, out_s, out_d);
  k_decode<<<256, 256, 0, stream>>>(out_s, out_d, amap, boxes, keys);

  k_sort_local<<<8, 1024, 0, stream>>>(keys);
  for (int k = 16384; k <= 65536; k <<= 1) {
    for (int j = k >> 1; j >= 8192; j >>= 1)
      k_sort_global<<<128, 256, 0, stream>>>(keys, k, j);
    k_sort_merge<<<8, 1024, 0, stream>>>(keys, k);
  }

  k_gather_sorted<<<24, 256, 0, stream>>>(keys, boxes, bx);
  k_nms_mask<<<6000, 128, 0, stream>>>(bx, mask);
  k_nms_scan<<<1, 64, 0, stream>>>(mask, sel);
  k_gather_prop<<<5, 64, 0, stream>>>(sel, bx, out_p, rois);

  hipMemsetAsync((char*)pooled + (size_t)300 * 25088 * 2, 0, (size_t)20 * 25088 * 2, stream);
  hipMemsetAsync(h1pre, 0, (size_t)320 * 4096 * 4, stream);

  k_roipool<<<300 * 98, 256, 0, stream>>>(fm, rois, pooled);

  if (fast) {
    k_bf16_cast<<<2048, 256, 0, stream>>>(fc1_w, fc1bf, 102760448);
    k_gemm4b<<<dim3(32, 8), 512, 0, stream>>>(pooled, fc1bf, h1pre, 25088, 3136, 4096);
    k_bias_relu_bf<<<5120, 256, 0, stream>>>(h1pre, fc1_b, h1bf);
    hipMemsetAsync(h2pre, 0, (size_t)320 * 4096 * 4, stream);
    k_bf16_cast<<<2048, 256, 0, stream>>>(fc2_w, fc2bf, 16777216);
    k_gemm4b<<<dim3(32, 8), 512, 0, stream>>>(h1bf, fc2bf, h2pre, 4096, 512, 4096);
  } else {
    k_gemm4f<<<dim3(32, 8), 512, 0, stream>>>(pooled, fc1_w, h1pre, 25088, 3136, 4096);
    k_bias_relu_bf<<<5120, 256, 0, stream>>>(h1pre, fc1_b, h1bf);
    hipMemsetAsync(h2pre, 0, (size_t)320 * 4096 * 4, stream);
    k_gemm4f<<<dim3(32, 8), 512, 0, stream>>>(h1bf, fc2_w, h2pre, 4096, 512, 4096);
  }
  k_bias_relu_bf<<<5120, 256, 0, stream>>>(h2pre, fc2_b, h2bf);
  k_head<<<300, 128, 0, stream>>>(h2bf, cw, cbias, rw, rbias, out_c, out_r);
}

// Round 11
// 939.931 us; speedup vs baseline: 1.1956x; 1.1956x over previous
//
#include <hip/hip_runtime.h>
#include <stdint.h>

typedef float f32x4 __attribute__((ext_vector_type(4)));
typedef float f32x2 __attribute__((ext_vector_type(2)));
typedef short s16x8 __attribute__((ext_vector_type(8)));
typedef unsigned long long u64;

__device__ __forceinline__ unsigned short f2bf(float f) {
  union { float f; unsigned u; } v; v.f = f;
  unsigned u = v.u;
  return (unsigned short)((u + 0x7FFFu + ((u >> 16) & 1u)) >> 16);
}
__device__ __forceinline__ float bf2f(unsigned short b) {
  union { unsigned u; float f; } v; v.u = ((unsigned)b) << 16; return v.f;
}

// ---------------- conv5: 3x3, 512->512, 64x64, SAME, K-split x4 --------------
// conv4 + LDS X pitch 20 (16B-aligned rows) + vectorized X reads
// (2xb128 + 1xb64 per row instead of 10xb32): cuts LDS-pipe pressure below
// the VALU floor. FMA order identical -> bit-identical output.
#define CONV_ICC 8
__global__ __launch_bounds__(256, 2) void k_conv5(const float* __restrict__ fm,
                                                  const float* __restrict__ w,
                                                  float* __restrict__ ypart) {
  __shared__ float Xs[2][CONV_ICC * 360];     // [buf][ic][18 rows][pitch 20]
  __shared__ float Ws[2][CONV_ICC * 9 * 64];  // [buf][ic][k][oc]
  int bid = blockIdx.x;
  int s = bid & 3, ocg = (bid >> 2) & 7, sp = bid >> 5;   // sp 0..15
  int h0 = (sp >> 2) * 16, w0 = (sp & 3) * 16;
  int oc0 = ocg * 64;
  int t = threadIdx.x;
  int g = t >> 5, p = t & 31;
  int row = p >> 1, colb = (p & 1) * 8;

  int xic[11], xoff[11], xlds[11]; bool xval[11], xact[11];
  #pragma unroll
  for (int i = 0; i < 11; i++) {
    int idx = t + i * 256;
    xact[i] = (idx < CONV_ICC * 324);
    if (xact[i]) {
      int ic = idx / 324, rem = idx - ic * 324;
      int r = rem / 18, cc = rem - r * 18;
      int gy = h0 + r - 1, gx = w0 + cc - 1;
      xval[i] = ((unsigned)gy < 64u) && ((unsigned)gx < 64u);
      xic[i] = ic;
      xoff[i] = xval[i] ? (gy * 64 + gx) : 0;
      xlds[i] = ic * 360 + r * 20 + cc;
    } else { xval[i] = false; xic[i] = 0; xoff[i] = 0; xlds[i] = 0; }
  }
  u64 wbase[18];
  #pragma unroll
  for (int i = 0; i < 18; i++) {
    int idx = t + i * 256;
    int oc = idx & 63, rest = idx >> 6;
    int ic = rest / 9, kk = rest - ic * 9;
    wbase[i] = (u64)(oc0 + oc) * 4608 + ic * 9 + kk;
  }

  float acc[8][8] = {};
  int cbase = s * 128;
  float XR[11], WR[18];

  {
    int c0 = cbase;
    #pragma unroll
    for (int i = 0; i < 11; i++)
      XR[i] = xval[i] ? fm[(u64)(c0 + xic[i]) * 4096 + xoff[i]] : 0.f;
    #pragma unroll
    for (int i = 0; i < 18; i++)
      WR[i] = w[wbase[i] + (u64)c0 * 9];
    #pragma unroll
    for (int i = 0; i < 11; i++) if (xact[i]) Xs[0][xlds[i]] = XR[i];
    #pragma unroll
    for (int i = 0; i < 18; i++) Ws[0][t + i * 256] = WR[i];
  }
  __syncthreads();

  int cur = 0;
  for (int chunk = 0; chunk < 16; chunk++) {
    bool pf = (chunk < 15);
    if (pf) {
      int cn = cbase + (chunk + 1) * CONV_ICC;
      #pragma unroll
      for (int i = 0; i < 11; i++)
        XR[i] = xval[i] ? fm[(u64)(cn + xic[i]) * 4096 + xoff[i]] : 0.f;
      #pragma unroll
      for (int i = 0; i < 18; i++)
        WR[i] = w[wbase[i] + (u64)cn * 9];
    }
    const float* XsC = Xs[cur];
    const float* WsC = Ws[cur];
    for (int ic = 0; ic < CONV_ICC; ic++) {
      const float* xb = &XsC[ic * 360 + colb];
      float xr[3][10];
      #pragma unroll
      for (int r = 0; r < 3; r++) {
        const float* rp = &xb[(row + r) * 20];
        f32x4 a = *(const f32x4*)rp;
        f32x4 b = *(const f32x4*)(rp + 4);
        f32x2 c = *(const f32x2*)(rp + 8);
        xr[r][0] = a.x; xr[r][1] = a.y; xr[r][2] = a.z; xr[r][3] = a.w;
        xr[r][4] = b.x; xr[r][5] = b.y; xr[r][6] = b.z; xr[r][7] = b.w;
        xr[r][8] = c.x; xr[r][9] = c.y;
      }
      #pragma unroll
      for (int kh = 0; kh < 3; kh++) {
        #pragma unroll
        for (int kw = 0; kw < 3; kw++) {
          const float* wp = &WsC[(ic * 9 + kh * 3 + kw) * 64 + g * 8];
          f32x4 wa = *(const f32x4*)wp;
          f32x4 wb = *(const f32x4*)(wp + 4);
          float wv[8] = {wa.x, wa.y, wa.z, wa.w, wb.x, wb.y, wb.z, wb.w};
          #pragma unroll
          for (int o = 0; o < 8; o++) {
            #pragma unroll
            for (int j = 0; j < 8; j++) {
              acc[o][j] += wv[o] * xr[kh][kw + j];
            }
          }
        }
      }
    }
    if (pf) {
      #pragma unroll
      for (int i = 0; i < 11; i++) if (xact[i]) Xs[cur ^ 1][xlds[i]] = XR[i];
      #pragma unroll
      for (int i = 0; i < 18; i++) Ws[cur ^ 1][t + i * 256] = WR[i];
    }
    __syncthreads();
    cur ^= 1;
  }

  float* yp = ypart + (u64)s * 2097152;
  #pragma unroll
  for (int j = 0; j < 8; j++) {
    int pxg = (h0 + row) * 64 + (w0 + colb + j);
    f32x4 v0, v1;
    v0.x = acc[0][j]; v0.y = acc[1][j]; v0.z = acc[2][j]; v0.w = acc[3][j];
    v1.x = acc[4][j]; v1.y = acc[5][j]; v1.z = acc[6][j]; v1.w = acc[7][j];
    f32x4* dst = (f32x4*)&yp[(u64)pxg * 512 + oc0 + g * 8];
    dst[0] = v0; dst[1] = v1;
  }
}

// --------------- 1x1 convs: sum partials + bias + relu, then dots ------------
__global__ __launch_bounds__(256) void k_rpn1x1(const float* __restrict__ ypart,
                                                const float* __restrict__ conv_b,
                                                const float* __restrict__ cw, const float* __restrict__ cb,
                                                const float* __restrict__ bw, const float* __restrict__ bb,
                                                float* __restrict__ out_s, float* __restrict__ out_d) {
  __shared__ float Ys[16 * 516];
  int px0 = blockIdx.x * 16;
  int t = threadIdx.x;
  for (int c = t; c < 16 * 128; c += 256) {
    int p = c >> 7, seg = c & 127;
    u64 off = (u64)(px0 + p) * 512 + seg * 4;
    f32x4 v0 = *(const f32x4*)&ypart[off];
    f32x4 v1 = *(const f32x4*)&ypart[2097152 + off];
    f32x4 v2 = *(const f32x4*)&ypart[2 * 2097152 + off];
    f32x4 v3 = *(const f32x4*)&ypart[3 * (u64)2097152 + off];
    f32x4 b = *(const f32x4*)&conv_b[seg * 4];
    f32x4 r;
    r.x = fmaxf(v0.x + v1.x + v2.x + v3.x + b.x, 0.f);
    r.y = fmaxf(v0.y + v1.y + v2.y + v3.y + b.y, 0.f);
    r.z = fmaxf(v0.z + v1.z + v2.z + v3.z + b.z, 0.f);
    r.w = fmaxf(v0.w + v1.w + v2.w + v3.w + b.w, 0.f);
    *(f32x4*)&Ys[p * 516 + seg * 4] = r;
  }
  __syncthreads();
  int px = t & 15, og = t >> 4;
  const float* yr = &Ys[px * 516];
  for (int n = og; n < 45; n += 16) {
    const float* wr = (n < 9) ? &cw[n * 512] : &bw[(n - 9) * 512];
    float acc = 0.f;
    for (int k = 0; k < 512; k += 4) {
      f32x4 wv = *(const f32x4*)&wr[k];
      acc += wv.x * yr[k] + wv.y * yr[k + 1] + wv.z * yr[k + 2] + wv.w * yr[k + 3];
    }
    int gpx = px0 + px;
    if (n < 9) {
      float s = acc + cb[n];
      out_s[gpx * 9 + n] = 1.f / (1.f + expf(-s));
    } else {
      out_d[gpx * 36 + (n - 9)] = acc + bb[n - 9];
    }
  }
}

// --------------- box decode + sort keys --------------------------------------
__global__ void k_decode(const float* __restrict__ sc, const float* __restrict__ dl,
                         const float* __restrict__ amap,
                         float* __restrict__ boxes, u64* __restrict__ keys) {
  int i = blockIdx.x * 256 + threadIdx.x;
  if (i >= 65536) return;
  if (i < 36864) {
    int px = i / 9, a = i - px * 9;
    const float* A = &amap[i * 4];
    const float* D = &dl[px * 36 + a * 4];
    float cy = A[0] + D[0] * A[2];
    float cx = A[1] + D[1] * A[3];
    float hh = A[2] * expf(D[2]);
    float ww = A[3] * expf(D[3]);
    float y1 = fminf(fmaxf(cy - 0.5f * hh, 0.f), 1023.f);
    float x1 = fminf(fmaxf(cx - 0.5f * ww, 0.f), 1023.f);
    float y2 = fminf(fmaxf(cy + 0.5f * hh, 0.f), 1023.f);
    float x2 = fminf(fmaxf(cx + 0.5f * ww, 0.f), 1023.f);
    f32x4 v; v.x = y1; v.y = x1; v.z = y2; v.w = x2;
    *(f32x4*)&boxes[i * 4] = v;
    unsigned bits = __float_as_uint(sc[i]);
    u64 key = ((u64)bits << 16) | (u64)(0xFFFFu - (unsigned)i);
    keys[i] = ~key;  // ascending sort of ~key == descending by (score, -idx)
  } else {
    keys[i] = ~0ull;
  }
}

// --------------- bitonic sort of 65536 u64 keys (ascending) ------------------
__global__ __launch_bounds__(1024) void k_sort_local(u64* __restrict__ keys) {
  __shared__ u64 S[8192];
  int base = blockIdx.x * 8192;
  for (int i = threadIdx.x; i < 8192; i += 1024) S[i] = keys[base + i];
  __syncthreads();
  for (int k = 2; k <= 8192; k <<= 1) {
    for (int j = k >> 1; j > 0; j >>= 1) {
      for (int p = threadIdx.x; p < 4096; p += 1024) {
        int i = ((p & ~(j - 1)) << 1) | (p & (j - 1));
        int ix = i | j;
        bool up = (((base + i) & k) == 0);
        u64 a = S[i], c = S[ix];
        if ((a > c) == up) { S[i] = c; S[ix] = a; }
      }
      __syncthreads();
    }
  }
  for (int i = threadIdx.x; i < 8192; i += 1024) keys[base + i] = S[i];
}

__global__ void k_sort_global(u64* __restrict__ keys, int k, int j) {
  int p = blockIdx.x * 256 + threadIdx.x;
  int i = ((p & ~(j - 1)) << 1) | (p & (j - 1));
  int ix = i | j;
  bool up = ((i & k) == 0);
  u64 a = keys[i], c = keys[ix];
  if ((a > c) == up) { keys[i] = c; keys[ix] = a; }
}

__global__ __launch_bounds__(1024) void k_sort_merge(u64* __restrict__ keys, int k) {
  __shared__ u64 S[8192];
  int base = blockIdx.x * 8192;
  for (int i = threadIdx.x; i < 8192; i += 1024) S[i] = keys[base + i];
  __syncthreads();
  for (int j = 4096; j > 0; j >>= 1) {
    for (int p = threadIdx.x; p < 4096; p += 1024) {
      int i = ((p & ~(j - 1)) << 1) | (p & (j - 1));
      int ix = i | j;
      bool up = (((base + i) & k) == 0);
      u64 a = S[i], c = S[ix];
      if ((a > c) == up) { S[i] = c; S[ix] = a; }
    }
    __syncthreads();
  }
  for (int i = threadIdx.x; i < 8192; i += 1024) keys[base + i] = S[i];
}

__global__ void k_gather_sorted(const u64* __restrict__ keys, const float* __restrict__ boxes,
                                float* __restrict__ bx) {
  int p = blockIdx.x * 256 + threadIdx.x;
  if (p >= 6000) return;
  u64 key = ~keys[p];
  int idx = 0xFFFF - (int)(key & 0xFFFFull);
  *(f32x4*)&bx[p * 4] = *(const f32x4*)&boxes[idx * 4];
}

// --------------- NMS: suppression bitmask + sequential scan ------------------
__global__ __launch_bounds__(128) void k_nms_mask(const float* __restrict__ bx, u64* __restrict__ mask) {
  int i = blockIdx.x;
  int w = threadIdx.x;
  if (w >= 94) return;
  f32x4 bi = *(const f32x4*)&bx[i * 4];
  float ai = (bi.z - bi.x) * (bi.w - bi.y);
  u64 m = 0;
  int j0 = w * 64;
  for (int b = 0; b < 64; b++) {
    int j = j0 + b;
    if (j >= 6000) break;
    if (j <= i) continue;
    f32x4 bj = *(const f32x4*)&bx[j * 4];
    float yy1 = fmaxf(bi.x, bj.x), xx1 = fmaxf(bi.y, bj.y);
    float yy2 = fminf(bi.z, bj.z), xx2 = fminf(bi.w, bj.w);
    float inter = fmaxf(yy2 - yy1, 0.f) * fmaxf(xx2 - xx1, 0.f);
    float aj = (bj.z - bj.x) * (bj.w - bj.y);
    float iou = inter / (ai + aj - inter + 1e-8f);
    if (iou > 0.7f) m |= (1ull << b);
  }
  mask[i * 94 + w] = m;
}

// Sequential greedy scan with EARLY EXIT (see R1 notes).
__global__ __launch_bounds__(64) void k_nms_scan(const u64* __restrict__ mask, int* __restrict__ sel) {
  int lane = threadIdx.x;
  u64 rem0 = 0, rem1 = 0;
  int nkeep = 0;
  u64 cur0[16], cur1[16], nxt0[16], nxt1[16];
  bool l30 = (lane < 30);
  #pragma unroll
  for (int r = 0; r < 16; r++) {
    cur0[r] = mask[r * 94 + lane];
    cur1[r] = l30 ? mask[r * 94 + 64 + lane] : 0ull;
  }
  for (int c0 = 0; c0 < 6000; c0 += 16) {
    int n0 = c0 + 16;
    if (n0 < 6000) {
      #pragma unroll
      for (int r = 0; r < 16; r++) {
        nxt0[r] = mask[(n0 + r) * 94 + lane];
        nxt1[r] = l30 ? mask[(n0 + r) * 94 + 64 + lane] : 0ull;
      }
    }
    #pragma unroll
    for (int r = 0; r < 16; r++) {
      int i = c0 + r;
      int wi = i >> 6, bi = i & 63;
      u64 wv = (wi < 64) ? __shfl(rem0, wi, 64) : __shfl(rem1, wi - 64, 64);
      if (!((wv >> bi) & 1ull)) {
        if (lane == 0 && nkeep < 300) sel[nkeep] = i;
        nkeep++;
        rem0 |= cur0[r]; rem1 |= cur1[r];
      }
    }
    if (nkeep >= 300) return;
    #pragma unroll
    for (int r = 0; r < 16; r++) { cur0[r] = nxt0[r]; cur1[r] = nxt1[r]; }
  }
  __shared__ u64 remS[94];
  remS[lane] = rem0;
  if (l30) remS[64 + lane] = rem1;
  __syncthreads();
  if (lane == 0) {
    int k = nkeep;
    for (int i = 0; i < 6000 && k < 300; i++) {
      if ((remS[i >> 6] >> (i & 63)) & 1ull) sel[k++] = i;
    }
  }
}

__global__ void k_gather_prop(const int* __restrict__ sel, const float* __restrict__ bx,
                              float* __restrict__ out_p, float* __restrict__ rois) {
  int r = blockIdx.x * 64 + threadIdx.x;
  if (r >= 300) return;
  int p = sel[r];
  float y1 = bx[p * 4 + 0], x1 = bx[p * 4 + 1], y2 = bx[p * 4 + 2], x2 = bx[p * 4 + 3];
  out_p[r * 4 + 0] = y1; out_p[r * 4 + 1] = x1; out_p[r * 4 + 2] = y2; out_p[r * 4 + 3] = x2;
  rois[r * 4 + 0] = x1; rois[r * 4 + 1] = y1; rois[r * 4 + 2] = x2; rois[r * 4 + 3] = y2;
}

// --------------- ROI max-pool 7x7 (exact ref semantics), out bf16 ------------
__global__ __launch_bounds__(256) void k_roipool(const float* __restrict__ fm,
                                                 const float* __restrict__ rois,
                                                 unsigned short* __restrict__ pooled) {
  int roi = blockIdx.x / 98;
  int seg = blockIdx.x - roi * 98;
  __shared__ int hs[7], he[7], wls[7], wle[7];
  if (threadIdx.x < 28) {
    int kind = threadIdx.x / 7, p = threadIdx.x - kind * 7;
    float x1 = rintf(rois[roi * 4 + 0] * 0.0625f);
    float y1 = rintf(rois[roi * 4 + 1] * 0.0625f);
    float x2 = rintf(rois[roi * 4 + 2] * 0.0625f);
    float y2 = rintf(rois[roi * 4 + 3] * 0.0625f);
    float rw = fmaxf(x2 - x1 + 1.f, 1.f), rh = fmaxf(y2 - y1 + 1.f, 1.f);
    float bh = rh / 7.f, bw = rw / 7.f;
    float fp = (float)p;
    if (kind == 0) hs[p]  = (int)fminf(fmaxf(floorf(fp * bh) + y1, 0.f), 64.f);
    if (kind == 1) he[p]  = (int)fminf(fmaxf(ceilf((fp + 1.f) * bh) + y1, 0.f), 64.f);
    if (kind == 2) wls[p] = (int)fminf(fmaxf(floorf(fp * bw) + x1, 0.f), 64.f);
    if (kind == 3) wle[p] = (int)fminf(fmaxf(ceilf((fp + 1.f) * bw) + x1, 0.f), 64.f);
  }
  __syncthreads();
  int o = seg * 256 + threadIdx.x;  // < 25088
  int c = o / 49; int cell = o - c * 49;
  int ph = cell / 7, pw = cell - ph * 7;
  int y0 = hs[ph], y1e = he[ph], x0 = wls[pw], x1e = wle[pw];
  bool any = (y1e > y0) && (x1e > x0);
  float m = -1e30f;
  const float* base = &fm[c * 4096];
  for (int yy = y0; yy < y1e; yy++)
    for (int xx = x0; xx < x1e; xx++)
      m = fmaxf(m, base[yy * 64 + xx]);
  pooled[(u64)roi * 25088 + o] = f2bf(any ? m : 0.f);
}

// --------------- big GEMM v4: depth-2 B pipeline, dbuf LDS -------------------
#define GEMM_ITERF(IT, BSLOT)                                                       \
  {                                                                                 \
    bool pf = ((IT) + 1 < n_it);                                                    \
    if (pf) {                                                                       \
      int kn = kbeg + ((IT) + 1) * 64;                                              \
      _Pragma("unroll")                                                             \
      for (int i = 0; i < 5; i++)                                                   \
        Araw[i] = *(const uint4*)&A[(u64)am[i] * K + kn + aks[i] * 8];              \
    }                                                                               \
    const unsigned short* ab = (const unsigned short*)Ab[cur];                      \
    const unsigned short* bb = (const unsigned short*)Bb[cur];                      \
    _Pragma("unroll")                                                               \
    for (int ksub = 0; ksub < 2; ksub++) {                                          \
      int ks = ksub * 4 + lk;                                                       \
      s16x8 bf0 = *(const s16x8*)&bb[(u64)(ks * 128 + ng * 32 + lr) * 8];           \
      s16x8 bf1 = *(const s16x8*)&bb[(u64)(ks * 128 + ng * 32 + 16 + lr) * 8];      \
      _Pragma("unroll")                                                             \
      for (int mt = 0; mt < 10; mt++) {                                             \
        s16x8 af = *(const s16x8*)&ab[(u64)(ks * 320 + m0 + mt * 16 + lr) * 8];     \
        acc[mt][0] = __builtin_amdgcn_mfma_f32_16x16x32_bf16(af, bf0, acc[mt][0], 0, 0, 0); \
        acc[mt][1] = __builtin_amdgcn_mfma_f32_16x16x32_bf16(af, bf1, acc[mt][1], 0, 0, 0); \
      }                                                                             \
    }                                                                               \
    if (pf) {                                                                       \
      _Pragma("unroll")                                                             \
      for (int i = 0; i < 5; i++) Ab[cur ^ 1][t + i * 512] = Araw[i];               \
      float fv[16] = {BSLOT[0].x, BSLOT[0].y, BSLOT[0].z, BSLOT[0].w,               \
                      BSLOT[1].x, BSLOT[1].y, BSLOT[1].z, BSLOT[1].w,               \
                      BSLOT[2].x, BSLOT[2].y, BSLOT[2].z, BSLOT[2].w,               \
                      BSLOT[3].x, BSLOT[3].y, BSLOT[3].z, BSLOT[3].w};              \
      _Pragma("unroll")                                                             \
      for (int h = 0; h < 2; h++) {                                                 \
        s16x8 pk;                                                                   \
        _Pragma("unroll")                                                           \
        for (int j = 0; j < 8; j++) pk[j] = (short)f2bf(fv[h * 8 + j]);             \
        *(s16x8*)&Bb[cur ^ 1][(bpart * 2 + h) * 128 + brow] = pk;                   \
      }                                                                             \
      if ((IT) + 3 < n_it) {                                                        \
        int k3 = kbeg + ((IT) + 3) * 64;                                            \
        _Pragma("unroll")                                                           \
        for (int q = 0; q < 4; q++) BSLOT[q] = *(const f32x4*)&gB[k3 + q * 4];      \
      }                                                                             \
    }                                                                               \
    __syncthreads();                                                                \
    cur ^= 1;                                                                       \
  }

__global__ __launch_bounds__(512, 1) void k_gemm4f(const unsigned short* __restrict__ A,
                                                   const float* __restrict__ B,
                                                   float* __restrict__ Cpre,
                                                   int K, int Kslice, int N) {
  __shared__ uint4 Ab[2][2560];
  __shared__ uint4 Bb[2][1024];
  int n0 = blockIdx.x * 128;
  int s = blockIdx.y;
  int t = threadIdx.x;
  int wave = t >> 6, lane = t & 63;
  int mg = wave & 1, ng = wave >> 1;
  int m0 = mg * 160;
  int lr = lane & 15, lk = lane >> 4;

  int am[5], aks[5];
  #pragma unroll
  for (int i = 0; i < 5; i++) { int idx = t + i * 512; am[i] = idx % 320; aks[i] = idx / 320; }
  int brow = t >> 2, bpart = t & 3;
  const float* gB = &B[(u64)(n0 + brow) * K + bpart * 16];

  f32x4 acc[10][2];
  #pragma unroll
  for (int mt = 0; mt < 10; mt++)
    for (int nt = 0; nt < 2; nt++) { acc[mt][nt].x = 0; acc[mt][nt].y = 0; acc[mt][nt].z = 0; acc[mt][nt].w = 0; }

  int kbeg = s * Kslice;
  int n_it = Kslice >> 6;
  uint4 Araw[5];
  f32x4 Braw0[4], Braw1[4];

  #pragma unroll
  for (int i = 0; i < 5; i++)
    Araw[i] = *(const uint4*)&A[(u64)am[i] * K + kbeg + aks[i] * 8];
  #pragma unroll
  for (int q = 0; q < 4; q++)
    Braw0[q] = *(const f32x4*)&gB[kbeg + q * 4];
  #pragma unroll
  for (int i = 0; i < 5; i++) Ab[0][t + i * 512] = Araw[i];
  {
    float fv[16] = {Braw0[0].x, Braw0[0].y, Braw0[0].z, Braw0[0].w,
                    Braw0[1].x, Braw0[1].y, Braw0[1].z, Braw0[1].w,
                    Braw0[2].x, Braw0[2].y, Braw0[2].z, Braw0[2].w,
                    Braw0[3].x, Braw0[3].y, Braw0[3].z, Braw0[3].w};
    #pragma unroll
    for (int h = 0; h < 2; h++) {
      s16x8 pk;
      #pragma unroll
      for (int j = 0; j < 8; j++) pk[j] = (short)f2bf(fv[h * 8 + j]);
      *(s16x8*)&Bb[0][(bpart * 2 + h) * 128 + brow] = pk;
    }
  }
  if (1 < n_it) {
    #pragma unroll
    for (int q = 0; q < 4; q++) Braw1[q] = *(const f32x4*)&gB[kbeg + 64 + q * 4];
  }
  if (2 < n_it) {
    #pragma unroll
    for (int q = 0; q < 4; q++) Braw0[q] = *(const f32x4*)&gB[kbeg + 128 + q * 4];
  }
  __syncthreads();

  int cur = 0;
  for (int itp = 0; itp < n_it; itp += 2) {
    GEMM_ITERF(itp, Braw1);
    if (itp + 1 < n_it) GEMM_ITERF(itp + 1, Braw0);
  }

  #pragma unroll
  for (int mt = 0; mt < 10; mt++)
    for (int nt = 0; nt < 2; nt++)
      for (int r = 0; r < 4; r++) {
        int m = m0 + mt * 16 + lk * 4 + r;
        int n = n0 + ng * 32 + nt * 16 + lr;
        atomicAdd(&Cpre[(u64)m * N + n], acc[mt][nt][r]);
      }
}

__global__ void k_bias_relu_bf(const float* __restrict__ pre, const float* __restrict__ bias,
                               unsigned short* __restrict__ outb) {
  int i = blockIdx.x * 256 + threadIdx.x;  // 320*4096 total
  float v = pre[i] + bias[i & 4095];
  outb[i] = f2bf(fmaxf(v, 0.f));
}

// --------------- heads: cls softmax + reg ------------------------------------
__global__ __launch_bounds__(128) void k_head(const unsigned short* __restrict__ h2,
                                              const float* __restrict__ cw, const float* __restrict__ cb,
                                              const float* __restrict__ rw, const float* __restrict__ rb,
                                              float* __restrict__ out_cls, float* __restrict__ out_reg) {
  __shared__ float Hs[4096];
  __shared__ float logits[101];
  __shared__ float es[21];
  int r = blockIdx.x, t = threadIdx.x;
  for (int c = t; c < 512; c += 128) {
    uint4 raw = *(const uint4*)&h2[(u64)r * 4096 + c * 8];
    unsigned short* sp = (unsigned short*)&raw;
    #pragma unroll
    for (int q = 0; q < 8; q++) Hs[c * 8 + q] = bf2f(sp[q]);
  }
  __syncthreads();
  for (int n = t; n < 101; n += 128) {
    const float* wrow = (n < 21) ? &cw[n * 4096] : &rw[(n - 21) * 4096];
    float acc = 0.f;
    for (int k = 0; k < 4096; k += 4) {
      f32x4 wv = *(const f32x4*)&wrow[k];
      acc += wv.x * Hs[k] + wv.y * Hs[k + 1] + wv.z * Hs[k + 2] + wv.w * Hs[k + 3];
    }
    acc += (n < 21) ? cb[n] : rb[n - 21];
    logits[n] = acc;
  }
  __syncthreads();
  if (t < 21) {
    float mx = logits[0];
    for (int q = 1; q < 21; q++) mx = fmaxf(mx, logits[q]);
    es[t] = expf(logits[t] - mx);
  }
  __syncthreads();
  if (t < 21) {
    float sum = 0.f;
    for (int q = 0; q < 21; q++) sum += es[q];
    out_cls[r * 21 + t] = es[t] / sum;
  }
  if (t >= 21 && t < 101) out_reg[r * 80 + (t - 21)] = logits[t];
}

// ------------------------------- launcher ------------------------------------
extern "C" void kernel_launch(void* const* d_in, const int* in_sizes, int n_in,
                              void* d_out, int out_size, void* d_ws, size_t ws_size,
                              hipStream_t stream) {
  (void)in_sizes; (void)n_in; (void)out_size; (void)ws_size;
  const float* fm     = (const float*)d_in[0];
  const float* amap   = (const float*)d_in[1];
  const float* conv_w = (const float*)d_in[3];
  const float* conv_b = (const float*)d_in[4];
  const float* cls_w  = (const float*)d_in[5];
  const float* cls_b  = (const float*)d_in[6];
  const float* box_w  = (const float*)d_in[7];
  const float* box_b  = (const float*)d_in[8];
  const float* fc1_w  = (const float*)d_in[9];
  const float* fc1_b  = (const float*)d_in[10];
  const float* fc2_w  = (const float*)d_in[11];
  const float* fc2_b  = (const float*)d_in[12];
  const float* cw     = (const float*)d_in[13];
  const float* cbias  = (const float*)d_in[14];
  const float* rw     = (const float*)d_in[15];
  const float* rbias  = (const float*)d_in[16];

  float* out_s = (float*)d_out;           // 36864
  float* out_d = out_s + 36864;           // 147456
  float* out_p = out_d + 147456;          // 1200
  float* out_c = out_p + 1200;            // 6300
  float* out_r = out_c + 6300;            // 24000

  char* ws = (char*)d_ws;
  // Overlay: ypart [0, 33,554,432) lives only conv5 -> rpn1x1.
  float* ypart = (float*)(ws + 0);                          // 4 x 8,388,608
  u64*   mask  = (u64*)  (ws + 0);                          // 4,512,000 (post-rpn1x1)
  unsigned short* pooled = (unsigned short*)(ws + 4718592); // 16,056,320 -> ends 20,774,912
  float* boxes = (float*)(ws + 20971520);                   // 589,824 -> 21,561,344
  u64*   keys  = (u64*)  (ws + 21561344);                   // 524,288 -> 22,085,632
  float* bx    = (float*)(ws + 22085632);                   // 96,000 -> 22,181,632
  int*   sel   = (int*)  (ws + 22181632);                   // 1,280
  float* rois  = (float*)(ws + 22182912);                   // 4,800
  float* h1pre = (float*)(ws + 22282240);                   // 5,242,880 -> 27,525,120
  unsigned short* h1bf = (unsigned short*)(ws + 27525120);  // 2,621,440 -> 30,146,560
  float* h2pre = h1pre;                                     // alias (re-zeroed mid-stream)
  unsigned short* h2bf = (unsigned short*)(ws + 30146560);  // 2,621,440 -> 32,768,000

  k_conv5<<<512, 256, 0, stream>>>(fm, conv_w, ypart);
  k_rpn1x1<<<256, 256, 0, stream>>>(ypart, conv_b, cls_w, cls_b, box_w, box_b, out_s, out_d);
  k_decode<<<256, 256, 0, stream>>>(out_s, out_d, amap, boxes, keys);

  k_sort_local<<<8, 1024, 0, stream>>>(keys);
  for (int k = 16384; k <= 65536; k <<= 1) {
    for (int j = k >> 1; j >= 8192; j >>= 1)
      k_sort_global<<<128, 256, 0, stream>>>(keys, k, j);
    k_sort_merge<<<8, 1024, 0, stream>>>(keys, k);
  }

  k_gather_sorted<<<24, 256, 0, stream>>>(keys, boxes, bx);
  k_nms_mask<<<6000, 128, 0, stream>>>(bx, mask);
  k_nms_scan<<<1, 64, 0, stream>>>(mask, sel);
  k_gather_prop<<<5, 64, 0, stream>>>(sel, bx, out_p, rois);

  // These live inside the ypart overlay region -> must run after rpn1x1.
  hipMemsetAsync((char*)pooled + (size_t)300 * 25088 * 2, 0, (size_t)20 * 25088 * 2, stream);
  hipMemsetAsync(h1pre, 0, (size_t)320 * 4096 * 4, stream);

  k_roipool<<<300 * 98, 256, 0, stream>>>(fm, rois, pooled);

  k_gemm4f<<<dim3(32, 8), 512, 0, stream>>>(pooled, fc1_w, h1pre, 25088, 3136, 4096);
  k_bias_relu_bf<<<5120, 256, 0, stream>>>(h1pre, fc1_b, h1bf);
  hipMemsetAsync(h2pre, 0, (size_t)320 * 4096 * 4, stream);
  k_gemm4f<<<dim3(32, 8), 512, 0, stream>>>(h1bf, fc2_w, h2pre, 4096, 512, 4096);
  k_bias_relu_bf<<<5120, 256, 0, stream>>>(h2pre, fc2_b, h2bf);
  k_head<<<300, 128, 0, stream>>>(h2bf, cw, cbias, rw, rbias, out_c, out_r);
}